// Round 13
// baseline (260.189 us; speedup 1.0000x reference)
//
#include <hip/hip_runtime.h>

#define NM 100000
#define NB 200000
#define NG 5000
#define NE1 400000
#define NE2 100000
#define NE (NE1 + NE2)
#define NMP 100004  // NM+1 rounded up to keep 16B alignment of later ws regions
#define SCAN_BLOCKS 391  // 391*256 = 100096 >= NM

typedef __attribute__((ext_vector_type(8))) short bf16x8;
typedef __attribute__((ext_vector_type(4))) short short4v;
typedef __attribute__((ext_vector_type(4))) float f32x4;

__device__ __forceinline__ unsigned short f2bf(float f) {
    unsigned int u = __float_as_uint(f);
    u += 0x7FFFu + ((u >> 16) & 1u);   // round-to-nearest-even
    return (unsigned short)(u >> 16);
}
__device__ __forceinline__ float bf2f(unsigned short u) {
    return __uint_as_float((unsigned int)u << 16);
}
__device__ __forceinline__ float elu_f(float x) {
    return x > 0.f ? x : __expf(x) - 1.f;
}
// swizzled LDS address within a wave-private tile: row j (128B), 16B-slot XOR (j&7)
__device__ __forceinline__ char* swz(char* base, int j, int byteoff) {
    return base + j * 128 + ((((byteoff >> 4) ^ (j & 7)) << 4) | (byteoff & 15));
}

// ---------------------------------------------------------------------------
// Weight prep (all 9 matrices in one launch): Wt[i][k] = bf16(W[k][i]), K=64.
// ---------------------------------------------------------------------------
struct WEnt { const float* W; short* o; int I; int off; };
struct WAll { WEnt e[9]; };

__global__ __launch_bounds__(256) void wprep_all_kernel(WAll a)
{
    const int idx = blockIdx.x * 256 + threadIdx.x;  // grid sized exactly
    #pragma unroll
    for (int j = 8; j >= 0; --j) {
        if (idx >= a.e[j].off) {
            const int local = idx - a.e[j].off;
            const int I = a.e[j].I;
            const int i = local >> 6, k = local & 63;
            a.e[j].o[local] = (short)f2bf(a.e[j].W[k * I + i]);
            break;
        }
    }
}

// eff[h][k] = sum_d W2[k][64h+d] * attn[h][d]   (folds layer-3 into a 64-vec)
__global__ __launch_bounds__(256) void eff_kernel(
    const float* __restrict__ W2,    // (64,256)
    const float* __restrict__ attn,  // (4,64)
    float* __restrict__ eff)         // (4,64)
{
    const int t = threadIdx.x;
    const int h = t >> 6, k = t & 63;
    const float* wrow = W2 + (k << 8) + (h << 6);
    const float* arow = attn + (h << 6);
    float s = 0.f;
    #pragma unroll 8
    for (int d = 0; d < 64; ++d) s = fmaf(wrow[d], arow[d], s);
    eff[(h << 6) + k] = s;
}

// ---------------------------------------------------------------------------
// WAVE-PRIVATE fused MLP (r12 restructure): each wave owns 16 rows end-to-end.
// B-operand = wave's 16-sample tile; A iterates feature groups (it-outer,
// one f32x4 acc live). ZERO __syncthreads (wave-private LDS quarters,
// within-wave lgkmcnt ordering). Kills both the barrier stalls and the
// register pressure that made (256,5/6) spill (r11/r12 lessons).
// ---------------------------------------------------------------------------
__global__ __launch_bounds__(256) void mlp_mfma_kernel(
    const float* __restrict__ x, int N,
    const short* __restrict__ W0t, const float* __restrict__ b0,
    const short* __restrict__ W1t, const float* __restrict__ b1,
    const short* __restrict__ W2t,
    const float* __restrict__ attn,    // (4,64) f32
    float* __restrict__ score,         // (N,4)
    unsigned short* __restrict__ ft_out) // (N,256) bf16
{
    __shared__ __attribute__((aligned(128))) char ldsA[64 * 128];
    __shared__ __attribute__((aligned(128))) char ldsB[64 * 128];

    const int tid = threadIdx.x;
    const int w = tid >> 6, l = tid & 63;
    const int g = l >> 4, c = l & 15;
    const int r0 = (blockIdx.x << 6) + (w << 4);   // wave's first row
    char* privA = ldsA + (w << 11);                // wave-private 2KB
    char* privB = ldsB + (w << 11);

    // ---- stage wave's 16 rows: f32 -> bf16, swizzled [j][k] ----
    {
        const int j = l >> 2, q = l & 3;           // 4 lanes per row
        const int row = r0 + j;
        bf16x8 o0 = (bf16x8)0, o1 = (bf16x8)0;
        if (row < N) {
            const float4* xp = (const float4*)(x + ((size_t)row << 6) + (q << 4));
            #pragma unroll
            for (int u = 0; u < 2; ++u) {
                float4 v = xp[u];
                o0[u*4+0] = (short)f2bf(v.x); o0[u*4+1] = (short)f2bf(v.y);
                o0[u*4+2] = (short)f2bf(v.z); o0[u*4+3] = (short)f2bf(v.w);
            }
            #pragma unroll
            for (int u = 0; u < 2; ++u) {
                float4 v = xp[u + 2];
                o1[u*4+0] = (short)f2bf(v.x); o1[u*4+1] = (short)f2bf(v.y);
                o1[u*4+2] = (short)f2bf(v.z); o1[u*4+3] = (short)f2bf(v.w);
            }
        }
        *(bf16x8*)swz(privA, j, q * 32)      = o0;
        *(bf16x8*)swz(privA, j, q * 32 + 16) = o1;
    }
    // no barrier: within-wave LDS dependency only

    // ---- layers 1 and 2 (64->64, ELU), wave-private ----
    char* src = privA;
    char* dst = privB;
    #pragma unroll
    for (int layer = 0; layer < 2; ++layer) {
        const short* Wt = layer ? W1t : W0t;
        const float* bb = layer ? b1 : b0;
        bf16x8 bfr[2];
        #pragma unroll
        for (int step = 0; step < 2; ++step)
            bfr[step] = *(const bf16x8*)swz(src, c, 64 * step + 16 * g);
        #pragma unroll
        for (int it = 0; it < 4; ++it) {
            f32x4 acc = {};
            #pragma unroll
            for (int step = 0; step < 2; ++step) {
                bf16x8 a = *(const bf16x8*)(Wt + (((16 * it + c) << 6) + 32 * step + 8 * g));
                acc = __builtin_amdgcn_mfma_f32_16x16x32_bf16(a, bfr[step], acc, 0, 0, 0);
            }
            const float4 bias = *(const float4*)(bb + 16 * it + 4 * g);
            short4v o;
            o[0] = (short)f2bf(elu_f(acc[0] + bias.x));
            o[1] = (short)f2bf(elu_f(acc[1] + bias.y));
            o[2] = (short)f2bf(elu_f(acc[2] + bias.z));
            o[3] = (short)f2bf(elu_f(acc[3] + bias.w));
            // sample row = c, features 16it+4g..+3 -> byte off 32it+8g
            *(short4v*)swz(dst, c, 32 * it + 8 * g) = o;
        }
        char* tmp = src; src = dst; dst = tmp;
    }

    // ---- layer 3 (64->256): 16 its, one acc live; ft + score partials ----
    {
        bf16x8 bfr[2];
        #pragma unroll
        for (int step = 0; step < 2; ++step)
            bfr[step] = *(const bf16x8*)swz(src, c, 64 * step + 16 * g);

        const int row_s = r0 + c;                  // this lane's sample
        float pt[4] = {0.f, 0.f, 0.f, 0.f};
        #pragma unroll
        for (int it = 0; it < 16; ++it) {
            f32x4 acc = {};
            #pragma unroll
            for (int step = 0; step < 2; ++step) {
                bf16x8 a = *(const bf16x8*)(W2t + (((16 * it + c) << 6) + 32 * step + 8 * g));
                acc = __builtin_amdgcn_mfma_f32_16x16x32_bf16(a, bfr[step], acc, 0, 0, 0);
            }
            const float4 av = *(const float4*)(attn + (it << 4) + (g << 2));
            pt[it >> 2] += acc[0] * av.x + acc[1] * av.y + acc[2] * av.z + acc[3] * av.w;
            if (row_s < N) {
                short4v o;
                o[0] = (short)f2bf(acc[0]);
                o[1] = (short)f2bf(acc[1]);
                o[2] = (short)f2bf(acc[2]);
                o[3] = (short)f2bf(acc[3]);
                *(short4v*)(ft_out + ((size_t)row_s << 8) + 16 * it + 4 * g) = o;
            }
        }
        // reduce over g (lanes with equal c), then lane g==0 stores float4
        #pragma unroll
        for (int h = 0; h < 4; ++h) {
            pt[h] += __shfl_xor(pt[h], 16);
            pt[h] += __shfl_xor(pt[h], 32);
        }
        if (g == 0 && row_s < N) {
            float4 sv = make_float4(pt[0], pt[1], pt[2], pt[3]);
            *(float4*)(score + (row_s << 2)) = sv;
        }
    }
}

// ---------------------------------------------------------------------------
// Master MLP (wave-private): layers 1-2, then er[row,h] = h2[row] . eff[h].
// ---------------------------------------------------------------------------
__global__ __launch_bounds__(256) void mlp2_score_kernel(
    const float* __restrict__ x, int N,
    const short* __restrict__ W0t, const float* __restrict__ b0,
    const short* __restrict__ W1t, const float* __restrict__ b1,
    const float* __restrict__ eff,   // (4,64) f32
    float* __restrict__ score)       // (N,4)
{
    __shared__ __attribute__((aligned(128))) char ldsA[64 * 128];
    __shared__ __attribute__((aligned(128))) char ldsB[64 * 128];

    const int tid = threadIdx.x;
    const int w = tid >> 6, l = tid & 63;
    const int g = l >> 4, c = l & 15;
    const int r0 = (blockIdx.x << 6) + (w << 4);
    char* privA = ldsA + (w << 11);
    char* privB = ldsB + (w << 11);

    // ---- stage wave's 16 rows ----
    {
        const int j = l >> 2, q = l & 3;
        const int row = r0 + j;
        bf16x8 o0 = (bf16x8)0, o1 = (bf16x8)0;
        if (row < N) {
            const float4* xp = (const float4*)(x + ((size_t)row << 6) + (q << 4));
            #pragma unroll
            for (int u = 0; u < 2; ++u) {
                float4 v = xp[u];
                o0[u*4+0] = (short)f2bf(v.x); o0[u*4+1] = (short)f2bf(v.y);
                o0[u*4+2] = (short)f2bf(v.z); o0[u*4+3] = (short)f2bf(v.w);
            }
            #pragma unroll
            for (int u = 0; u < 2; ++u) {
                float4 v = xp[u + 2];
                o1[u*4+0] = (short)f2bf(v.x); o1[u*4+1] = (short)f2bf(v.y);
                o1[u*4+2] = (short)f2bf(v.z); o1[u*4+3] = (short)f2bf(v.w);
            }
        }
        *(bf16x8*)swz(privA, j, q * 32)      = o0;
        *(bf16x8*)swz(privA, j, q * 32 + 16) = o1;
    }

    // ---- layers 1 and 2 (64->64, ELU), wave-private ----
    char* src = privA;
    char* dst = privB;
    #pragma unroll
    for (int layer = 0; layer < 2; ++layer) {
        const short* Wt = layer ? W1t : W0t;
        const float* bb = layer ? b1 : b0;
        bf16x8 bfr[2];
        #pragma unroll
        for (int step = 0; step < 2; ++step)
            bfr[step] = *(const bf16x8*)swz(src, c, 64 * step + 16 * g);
        #pragma unroll
        for (int it = 0; it < 4; ++it) {
            f32x4 acc = {};
            #pragma unroll
            for (int step = 0; step < 2; ++step) {
                bf16x8 a = *(const bf16x8*)(Wt + (((16 * it + c) << 6) + 32 * step + 8 * g));
                acc = __builtin_amdgcn_mfma_f32_16x16x32_bf16(a, bfr[step], acc, 0, 0, 0);
            }
            const float4 bias = *(const float4*)(bb + 16 * it + 4 * g);
            short4v o;
            o[0] = (short)f2bf(elu_f(acc[0] + bias.x));
            o[1] = (short)f2bf(elu_f(acc[1] + bias.y));
            o[2] = (short)f2bf(elu_f(acc[2] + bias.z));
            o[3] = (short)f2bf(elu_f(acc[3] + bias.w));
            *(short4v*)swz(dst, c, 32 * it + 8 * g) = o;
        }
        char* tmp = src; src = dst; dst = tmp;
    }

    // ---- epilogue: er = h2 . eff[h]; lane: sample j=l>>2, head h=l&3 ----
    {
        const int j = l >> 2, h = l & 3;
        const int row = r0 + j;
        float s = 0.f;
        #pragma unroll
        for (int c8 = 0; c8 < 8; ++c8) {
            bf16x8 v = *(const bf16x8*)swz(src, j, c8 * 16);
            const float4 e0 = *(const float4*)(eff + (h << 6) + (c8 << 3));
            const float4 e1 = *(const float4*)(eff + (h << 6) + (c8 << 3) + 4);
            s += bf2f((unsigned short)v[0]) * e0.x + bf2f((unsigned short)v[1]) * e0.y
               + bf2f((unsigned short)v[2]) * e0.z + bf2f((unsigned short)v[3]) * e0.w
               + bf2f((unsigned short)v[4]) * e1.x + bf2f((unsigned short)v[5]) * e1.y
               + bf2f((unsigned short)v[6]) * e1.z + bf2f((unsigned short)v[7]) * e1.w;
        }
        if (row < N) score[(row << 2) + h] = s;
    }
}

// ---------------------------------------------------------------------------
// CSR build: histogram -> 3-phase parallel scan -> fill (+ per-edge logits)
// ---------------------------------------------------------------------------
__global__ void hist_kernel(const int* __restrict__ e1_dst,
                            const int* __restrict__ e2_dst,
                            int* __restrict__ counts)
{
    int i = blockIdx.x * blockDim.x + threadIdx.x;
    if (i < NE1) atomicAdd(&counts[e1_dst[i]], 1);
    else if (i < NE) atomicAdd(&counts[e2_dst[i - NE1]], 1);
}

// phase 1: per-block inclusive prefix + block totals
__global__ __launch_bounds__(256) void scan1_kernel(
    const int* __restrict__ counts,
    int* __restrict__ prefix_inc,
    int* __restrict__ blocksums)
{
    const int i = blockIdx.x * 256 + threadIdx.x;
    const int lane = threadIdx.x & 63, wv = threadIdx.x >> 6;
    int v = (i < NM) ? counts[i] : 0;
    int x = v;
    #pragma unroll
    for (int o = 1; o < 64; o <<= 1) {
        int u = __shfl_up(x, o);
        if (lane >= o) x += u;
    }
    __shared__ int wsum[4];
    if (lane == 63) wsum[wv] = x;
    __syncthreads();
    int add = 0;
    #pragma unroll
    for (int k = 0; k < 3; ++k) add += (k < wv) ? wsum[k] : 0;
    x += add;
    if (i < NM) prefix_inc[i] = x;
    if (threadIdx.x == 255) blocksums[blockIdx.x] = x;
}

// phase 2: exclusive scan of the 391 block totals (one block)
__global__ __launch_bounds__(512) void scan2_kernel(int* __restrict__ blocksums)
{
    const int t = threadIdx.x;
    const int lane = t & 63, wv = t >> 6;
    int v = (t < SCAN_BLOCKS) ? blocksums[t] : 0;
    int x = v;
    #pragma unroll
    for (int o = 1; o < 64; o <<= 1) {
        int u = __shfl_up(x, o);
        if (lane >= o) x += u;
    }
    __shared__ int wsum[8];
    if (lane == 63) wsum[wv] = x;
    __syncthreads();
    int add = 0;
    #pragma unroll
    for (int k = 0; k < 7; ++k) add += (k < wv) ? wsum[k] : 0;
    x += add;
    if (t < SCAN_BLOCKS) blocksums[t] = x - v;  // exclusive
}

// phase 3: offsets[i] = inclusive[i] - counts[i] + blockbase; init cursor
__global__ __launch_bounds__(256) void scan3_kernel(
    const int* __restrict__ counts,
    const int* __restrict__ prefix_inc,
    const int* __restrict__ blocksums,
    int* __restrict__ offsets,
    int* __restrict__ cursor)
{
    const int i = blockIdx.x * 256 + threadIdx.x;
    if (i > NM) return;
    if (i == NM) { offsets[NM] = NE; return; }
    const int off = prefix_inc[i] - counts[i] + blocksums[blockIdx.x];
    offsets[i] = off;
    cursor[i]  = off;
}

// fill: place edge into CSR slot with UNIFIED ft row index (bond: src,
// glob: NB+src) AND compute v = leaky(el[src] + er[dst]) for 4 heads.
__global__ void fill_kernel(const int* __restrict__ e1_src,
                            const int* __restrict__ e1_dst,
                            const int* __restrict__ e2_src,
                            const int* __restrict__ e2_dst,
                            const float* __restrict__ er,
                            const float* __restrict__ el_b,
                            const float* __restrict__ el_g,
                            int* __restrict__ cursor,
                            int* __restrict__ rows,
                            float4* __restrict__ vsort)
{
    int i = blockIdx.x * blockDim.x + threadIdx.x;
    if (i >= NE) return;
    int dst, src, row;
    const float* el;
    if (i < NE1) { src = e1_src[i]; dst = e1_dst[i]; row = src;      el = el_b; }
    else { int j = i - NE1; src = e2_src[j]; dst = e2_dst[j]; row = NB + src; el = el_g; }
    const float4 l4 = *(const float4*)(el + (src << 2));
    const float4 r4 = *(const float4*)(er + (dst << 2));
    float4 v;
    v.x = l4.x + r4.x; v.x = v.x > 0.f ? v.x : 0.2f * v.x;
    v.y = l4.y + r4.y; v.y = v.y > 0.f ? v.y : 0.2f * v.y;
    v.z = l4.z + r4.z; v.z = v.z > 0.f ? v.z : 0.2f * v.z;
    v.w = l4.w + r4.w; v.w = v.w > 0.f ? v.w : 0.2f * v.w;
    int p = atomicAdd(&cursor[dst], 1);
    rows[p] = row;
    vsort[p] = v;
}

// ---------------------------------------------------------------------------
// Aggregation: ONE WAVE per node, 4 nodes per block, single pass, no max
// shift (softmax shift-invariant; logits O(+-10), safe in f32).
// BATCHED GATHER: per 16-edge chunk, lanes 0..15 load rows/logits
// (coalesced), shfl-broadcast, then ALL <=16 ft gathers issued back-to-back.
// ---------------------------------------------------------------------------
__global__ __launch_bounds__(256) void aggregate_kernel(
    const int* __restrict__ offsets,
    const int* __restrict__ rows,           // (NE) unified ft row per CSR slot
    const float* __restrict__ vsort,        // (NE,4)
    const unsigned short* __restrict__ ft,  // (NB+NG,256) bf16 unified
    float* __restrict__ out)                // (NM,256)
{
    const int w = threadIdx.x >> 6, l = threadIdx.x & 63;
    const int h   = l >> 4;      // head for this lane
    const int e16 = l & 15;      // lane's slot within a 16-edge batch
    const int f4  = l << 2;      // feature base

    const int n = (blockIdx.x << 2) + w;
    if (n >= NM) return;

    const int start = offsets[n];
    const int deg   = offsets[n + 1] - start;

    f32x4 o = {};
    float s = 0.f;
    for (int b = 0; b < deg; b += 16) {
        const int rem = min(deg - b, 16);
        int   row_l = 0;
        float v_l   = 0.f;
        if (e16 < rem) {
            row_l = rows[start + b + e16];
            v_l   = vsort[((start + b + e16) << 2) + h];
        }
        short4v ftv[16];
        #pragma unroll
        for (int e = 0; e < 16; ++e) {
            if (e < rem) {
                const int row = __shfl(row_l, e);
                ftv[e] = *(const short4v*)(ft + ((size_t)row << 8) + f4);
            }
        }
        #pragma unroll
        for (int e = 0; e < 16; ++e) {
            if (e < rem) {
                const float wgt = __expf(__shfl(v_l, (h << 4) + e));
                s += wgt;
                o[0] = fmaf(bf2f((unsigned short)ftv[e][0]), wgt, o[0]);
                o[1] = fmaf(bf2f((unsigned short)ftv[e][1]), wgt, o[1]);
                o[2] = fmaf(bf2f((unsigned short)ftv[e][2]), wgt, o[2]);
                o[3] = fmaf(bf2f((unsigned short)ftv[e][3]), wgt, o[3]);
            }
        }
    }
    if (deg > 0) {
        const float inv = 1.f / s;
        o[0] *= inv; o[1] *= inv; o[2] *= inv; o[3] *= inv;
    }
    __builtin_nontemporal_store(o, (f32x4*)(out + ((size_t)n << 8) + f4));
}

// ---------------------------------------------------------------------------
extern "C" void kernel_launch(void* const* d_in, const int* in_sizes, int n_in,
                              void* d_out, int out_size, void* d_ws, size_t ws_size,
                              hipStream_t stream)
{
    const float* master = (const float*)d_in[0];
    const float* bond   = (const float*)d_in[1];
    const float* glob   = (const float*)d_in[2];
    const float* aW0 = (const float*)d_in[3];
    const float* ab0 = (const float*)d_in[4];
    const float* aW1 = (const float*)d_in[5];
    const float* ab1 = (const float*)d_in[6];
    const float* aW2 = (const float*)d_in[7];
    const float* bW0 = (const float*)d_in[8];
    const float* bb0 = (const float*)d_in[9];
    const float* bW1 = (const float*)d_in[10];
    const float* bb1 = (const float*)d_in[11];
    const float* bW2 = (const float*)d_in[12];
    const float* gW0 = (const float*)d_in[13];
    const float* gb0 = (const float*)d_in[14];
    const float* gW1 = (const float*)d_in[15];
    const float* gb1 = (const float*)d_in[16];
    const float* gW2 = (const float*)d_in[17];
    const float* attn_l = (const float*)d_in[18];
    const float* attn_r = (const float*)d_in[19];
    const int* e1_src = (const int*)d_in[20];
    const int* e1_dst = (const int*)d_in[21];
    const int* e2_src = (const int*)d_in[22];
    const int* e2_dst = (const int*)d_in[23];
    float* out = (float*)d_out;

    // workspace layout
    float* ws   = (float*)d_ws;
    unsigned short* ft_b = (unsigned short*)ws;          // NB*256 bf16
    unsigned short* ft_g = ft_b + (size_t)NB * 256;      // NG*256 bf16 (adjacent => unified)
    float* er   = (float*)(ft_g + (size_t)NG * 256);     // NM*4
    float* el_b = er + (size_t)NM * 4;                   // NB*4
    float* el_g = el_b + (size_t)NB * 4;                 // NG*4
    int* counts  = (int*)(el_g + (size_t)NG * 4);        // NMP
    int* offsets = counts + NMP;                         // NMP
    int* cursor  = offsets + NMP;                        // NMP
    int* rows    = cursor + NMP;                         // NE
    float4* vsort = (float4*)(rows + NE);                // NE float4 (16B aligned)
    int* prefix_inc = (int*)(vsort + NE);                // NMP
    int* blocksums  = prefix_inc + NMP;                  // 512
    float* effR = (float*)(blocksums + 512);             // 256 f32
    short* wtA = (short*)(effR + 256);                   // 24576 shorts
    short* wtB = wtA + 24576;
    short* wtG = wtB + 24576;

    hipMemsetAsync(counts, 0, sizeof(int) * NM, stream);

    // fused weight prep: 9 transposed bf16 matrices, one launch
    WAll wa;
    wa.e[0] = {aW0, wtA,          64,     0};
    wa.e[1] = {aW1, wtA + 4096,   64,  4096};
    wa.e[2] = {aW2, wtA + 8192,  256,  8192};
    wa.e[3] = {bW0, wtB,          64, 24576};
    wa.e[4] = {bW1, wtB + 4096,   64, 28672};
    wa.e[5] = {bW2, wtB + 8192,  256, 32768};
    wa.e[6] = {gW0, wtG,          64, 49152};
    wa.e[7] = {gW1, wtG + 4096,   64, 53248};
    wa.e[8] = {gW2, wtG + 8192,  256, 57344};
    wprep_all_kernel<<<288, 256, 0, stream>>>(wa);
    eff_kernel<<<1, 256, 0, stream>>>(aW2, attn_r, effR);

    mlp2_score_kernel<<<(NM + 63) / 64, 256, 0, stream>>>(
        master, NM, wtA, ab0, wtA + 4096, ab1, effR, er);
    mlp_mfma_kernel<<<(NB + 63) / 64, 256, 0, stream>>>(
        bond, NB, wtB, bb0, wtB + 4096, bb1, wtB + 8192, attn_l, el_b, ft_b);
    mlp_mfma_kernel<<<(NG + 63) / 64, 256, 0, stream>>>(
        glob, NG, wtG, gb0, wtG + 4096, gb1, wtG + 8192, attn_l, el_g, ft_g);

    hist_kernel<<<(NE + 255) / 256, 256, 0, stream>>>(e1_dst, e2_dst, counts);
    scan1_kernel<<<SCAN_BLOCKS, 256, 0, stream>>>(counts, prefix_inc, blocksums);
    scan2_kernel<<<1, 512, 0, stream>>>(blocksums);
    scan3_kernel<<<SCAN_BLOCKS + 1, 256, 0, stream>>>(counts, prefix_inc, blocksums,
                                                      offsets, cursor);
    fill_kernel<<<(NE + 255) / 256, 256, 0, stream>>>(e1_src, e1_dst, e2_src, e2_dst,
                                                      er, el_b, el_g,
                                                      cursor, rows, vsort);
    aggregate_kernel<<<(NM + 3) / 4, 256, 0, stream>>>(offsets, rows,
                                                       (const float*)vsort,
                                                       ft_b, out);
}

// Round 14
// 258.981 us; speedup vs baseline: 1.0047x; 1.0047x over previous
//
#include <hip/hip_runtime.h>

#define NM 100000
#define NB 200000
#define NG 5000
#define NE1 400000
#define NE2 100000
#define NE (NE1 + NE2)
#define NMP 100004
#define SCAN_BLOCKS 391  // 391*256 >= NM

typedef __attribute__((ext_vector_type(8))) short bf16x8;
typedef __attribute__((ext_vector_type(4))) short short4v;
typedef __attribute__((ext_vector_type(4))) float f32x4;

__device__ __forceinline__ unsigned short f2bf(float f) {
    unsigned int u = __float_as_uint(f);
    u += 0x7FFFu + ((u >> 16) & 1u);
    return (unsigned short)(u >> 16);
}
__device__ __forceinline__ float bf2f(unsigned short u) {
    return __uint_as_float((unsigned int)u << 16);
}
__device__ __forceinline__ float elu_f(float x) {
    return x > 0.f ? x : __expf(x) - 1.f;
}
// swizzled LDS address: activation tile row j (128B), 16B-slot XOR by (j&7)
__device__ __forceinline__ char* swz(char* base, int j, int byteoff) {
    return base + j * 128 + ((((byteoff >> 4) ^ (j & 7)) << 4) | (byteoff & 15));
}

// ---------------------------------------------------------------------------
// Weight prep: 6 matrices (W0,W1 x atom/bond/glob): Wt[i][k]=bf16(W[k][i]).
// ---------------------------------------------------------------------------
struct WEnt { const float* W; short* o; int I; int off; };
struct WAll { WEnt e[6]; };

__global__ __launch_bounds__(256) void wprep_all_kernel(WAll a)
{
    const int idx = blockIdx.x * 256 + threadIdx.x;  // grid sized exactly (24576)
    #pragma unroll
    for (int j = 5; j >= 0; --j) {
        if (idx >= a.e[j].off) {
            const int local = idx - a.e[j].off;
            const int I = a.e[j].I;
            const int i = local >> 6, k = local & 63;
            a.e[j].o[local] = (short)f2bf(a.e[j].W[k * I + i]);
            break;
        }
    }
}

// stacked transform weight: Wt2[i=0..255][k=0..127], k<64 -> W2_b, else W2_g
__global__ __launch_bounds__(256) void wt2prep_kernel(
    const float* __restrict__ W2b, const float* __restrict__ W2g,
    short* __restrict__ wt2)
{
    const int idx = blockIdx.x * 256 + threadIdx.x;  // 32768 total
    const int i = idx >> 7, k = idx & 127;
    const float v = (k < 64) ? W2b[(k << 8) + i] : W2g[((k - 64) << 8) + i];
    wt2[idx] = (short)f2bf(v);
}

// eff[h][k] = sum_d W2[k][64h+d] * attn[h][d]
__global__ __launch_bounds__(256) void eff_kernel(
    const float* __restrict__ W2, const float* __restrict__ attn,
    float* __restrict__ eff)
{
    const int t = threadIdx.x;
    const int h = t >> 6, k = t & 63;
    const float* wrow = W2 + (k << 8) + (h << 6);
    const float* arow = attn + (h << 6);
    float s = 0.f;
    #pragma unroll 8
    for (int d = 0; d < 64; ++d) s = fmaf(wrow[d], arow[d], s);
    eff[(h << 6) + k] = s;
}

// ---------------------------------------------------------------------------
// MLP layers 1-2 (r10 block structure, best known) + score via eff +
// OPTIONAL h2 write (bf16 (N,64) linear). Layer-3 is algebraically folded:
// score = h2 . eff[h]; ft is never materialized (r13 h2-space restructure).
// ---------------------------------------------------------------------------
__global__ __launch_bounds__(256, 4) void mlp2_kernel(
    const float* __restrict__ x, int N,
    const short* __restrict__ W0t, const float* __restrict__ b0,
    const short* __restrict__ W1t, const float* __restrict__ b1,
    const float* __restrict__ eff,       // (4,64) f32
    float* __restrict__ score,           // (N,4)
    unsigned short* __restrict__ h2_out) // (N,64) bf16 or nullptr
{
    __shared__ __attribute__((aligned(128))) char ldsA[64 * 128];
    __shared__ __attribute__((aligned(128))) char ldsB[64 * 128];

    const int tid = threadIdx.x;
    const int w = tid >> 6, l = tid & 63;
    const int g = l >> 4, c = l & 15;
    const int r0 = blockIdx.x << 6;

    // ---- stage x tile: f32 -> bf16, swizzled [j][k] ----
    {
        const int j = tid >> 2, q = tid & 3;
        const int row = r0 + j;
        bf16x8 o0 = (bf16x8)0, o1 = (bf16x8)0;
        if (row < N) {
            const float4* xp = (const float4*)(x + ((size_t)row << 6) + (q << 4));
            #pragma unroll
            for (int u = 0; u < 2; ++u) {
                float4 v = xp[u];
                o0[u*4+0] = (short)f2bf(v.x); o0[u*4+1] = (short)f2bf(v.y);
                o0[u*4+2] = (short)f2bf(v.z); o0[u*4+3] = (short)f2bf(v.w);
            }
            #pragma unroll
            for (int u = 0; u < 2; ++u) {
                float4 v = xp[u + 2];
                o1[u*4+0] = (short)f2bf(v.x); o1[u*4+1] = (short)f2bf(v.y);
                o1[u*4+2] = (short)f2bf(v.z); o1[u*4+3] = (short)f2bf(v.w);
            }
        }
        *(bf16x8*)swz(ldsA, j, q * 32)      = o0;
        *(bf16x8*)swz(ldsA, j, q * 32 + 16) = o1;
    }
    __syncthreads();

    // ---- layers 1 and 2 (64->64, ELU) ----
    char* src = ldsA;
    char* dst = ldsB;
    #pragma unroll
    for (int layer = 0; layer < 2; ++layer) {
        const short* Wt = layer ? W1t : W0t;
        const float* bb = layer ? b1 : b0;
        f32x4 acc[4] = {};
        #pragma unroll
        for (int step = 0; step < 2; ++step) {
            bf16x8 a = *(const bf16x8*)(Wt + (((16 * w + c) << 6) + 32 * step + 8 * g));
            #pragma unroll
            for (int t = 0; t < 4; ++t) {
                const int j = 16 * t + c;
                bf16x8 b = *(const bf16x8*)swz(src, j, 64 * step + 16 * g);
                acc[t] = __builtin_amdgcn_mfma_f32_16x16x32_bf16(a, b, acc[t], 0, 0, 0);
            }
        }
        const int i0 = 16 * w + 4 * g;
        const float4 bias = *(const float4*)(bb + i0);
        #pragma unroll
        for (int t = 0; t < 4; ++t) {
            const int j = 16 * t + c;
            short4v o;
            o[0] = (short)f2bf(elu_f(acc[t][0] + bias.x));
            o[1] = (short)f2bf(elu_f(acc[t][1] + bias.y));
            o[2] = (short)f2bf(elu_f(acc[t][2] + bias.z));
            o[3] = (short)f2bf(elu_f(acc[t][3] + bias.w));
            *(short4v*)swz(dst, j, 32 * w + 8 * g) = o;
        }
        __syncthreads();
        char* tmp = src; src = dst; dst = tmp;
    }

    // ---- epilogue 1: score[row,h] = h2[row] . eff[h] ----
    {
        const int j = tid >> 2, h = tid & 3;
        const int row = r0 + j;
        float s = 0.f;
        #pragma unroll
        for (int c8 = 0; c8 < 8; ++c8) {
            bf16x8 v = *(const bf16x8*)swz(src, j, c8 * 16);
            const float4 e0 = *(const float4*)(eff + (h << 6) + (c8 << 3));
            const float4 e1 = *(const float4*)(eff + (h << 6) + (c8 << 3) + 4);
            s += bf2f((unsigned short)v[0]) * e0.x + bf2f((unsigned short)v[1]) * e0.y
               + bf2f((unsigned short)v[2]) * e0.z + bf2f((unsigned short)v[3]) * e0.w
               + bf2f((unsigned short)v[4]) * e1.x + bf2f((unsigned short)v[5]) * e1.y
               + bf2f((unsigned short)v[6]) * e1.z + bf2f((unsigned short)v[7]) * e1.w;
        }
        if (row < N) score[(row << 2) + h] = s;
    }

    // ---- epilogue 2: h2 write-out (bf16 linear (N,64)) ----
    if (h2_out) {
        const int j = tid >> 2, q = tid & 3;
        const int row = r0 + j;
        if (row < N) {
            bf16x8 v0 = *(const bf16x8*)swz(src, j, q * 32);
            bf16x8 v1 = *(const bf16x8*)swz(src, j, q * 32 + 16);
            unsigned short* p = h2_out + ((size_t)row << 6) + (q << 4);
            *(bf16x8*)p       = v0;
            *(bf16x8*)(p + 8) = v1;
        }
    }
}

// ---------------------------------------------------------------------------
// CSR build: histogram -> 3-phase parallel scan -> fill (+ per-edge logits)
// ---------------------------------------------------------------------------
__global__ void hist_kernel(const int* __restrict__ e1_dst,
                            const int* __restrict__ e2_dst,
                            int* __restrict__ counts)
{
    int i = blockIdx.x * blockDim.x + threadIdx.x;
    if (i < NE1) atomicAdd(&counts[e1_dst[i]], 1);
    else if (i < NE) atomicAdd(&counts[e2_dst[i - NE1]], 1);
}

__global__ __launch_bounds__(256) void scan1_kernel(
    const int* __restrict__ counts,
    int* __restrict__ prefix_inc,
    int* __restrict__ blocksums)
{
    const int i = blockIdx.x * 256 + threadIdx.x;
    const int lane = threadIdx.x & 63, wv = threadIdx.x >> 6;
    int v = (i < NM) ? counts[i] : 0;
    int x = v;
    #pragma unroll
    for (int o = 1; o < 64; o <<= 1) {
        int u = __shfl_up(x, o);
        if (lane >= o) x += u;
    }
    __shared__ int wsum[4];
    if (lane == 63) wsum[wv] = x;
    __syncthreads();
    int add = 0;
    #pragma unroll
    for (int k = 0; k < 3; ++k) add += (k < wv) ? wsum[k] : 0;
    x += add;
    if (i < NM) prefix_inc[i] = x;
    if (threadIdx.x == 255) blocksums[blockIdx.x] = x;
}

__global__ __launch_bounds__(512) void scan2_kernel(int* __restrict__ blocksums)
{
    const int t = threadIdx.x;
    const int lane = t & 63, wv = t >> 6;
    int v = (t < SCAN_BLOCKS) ? blocksums[t] : 0;
    int x = v;
    #pragma unroll
    for (int o = 1; o < 64; o <<= 1) {
        int u = __shfl_up(x, o);
        if (lane >= o) x += u;
    }
    __shared__ int wsum[8];
    if (lane == 63) wsum[wv] = x;
    __syncthreads();
    int add = 0;
    #pragma unroll
    for (int k = 0; k < 7; ++k) add += (k < wv) ? wsum[k] : 0;
    x += add;
    if (t < SCAN_BLOCKS) blocksums[t] = x - v;  // exclusive
}

__global__ __launch_bounds__(256) void scan3_kernel(
    const int* __restrict__ counts,
    const int* __restrict__ prefix_inc,
    const int* __restrict__ blocksums,
    int* __restrict__ offsets,
    int* __restrict__ cursor)
{
    const int i = blockIdx.x * 256 + threadIdx.x;
    if (i > NM) return;
    if (i == NM) { offsets[NM] = NE; return; }
    const int off = prefix_inc[i] - counts[i] + blocksums[blockIdx.x];
    offsets[i] = off;
    cursor[i]  = off;
}

// fill: CSR slot with UNIFIED h2 row (bond: src, glob: NB+src) + logits.
__global__ void fill_kernel(const int* __restrict__ e1_src,
                            const int* __restrict__ e1_dst,
                            const int* __restrict__ e2_src,
                            const int* __restrict__ e2_dst,
                            const float* __restrict__ er,
                            const float* __restrict__ el_b,
                            const float* __restrict__ el_g,
                            int* __restrict__ cursor,
                            int* __restrict__ rows,
                            float4* __restrict__ vsort)
{
    int i = blockIdx.x * blockDim.x + threadIdx.x;
    if (i >= NE) return;
    int dst, src, row;
    const float* el;
    if (i < NE1) { src = e1_src[i]; dst = e1_dst[i]; row = src;      el = el_b; }
    else { int j = i - NE1; src = e2_src[j]; dst = e2_dst[j]; row = NB + src; el = el_g; }
    const float4 l4 = *(const float4*)(el + (src << 2));
    const float4 r4 = *(const float4*)(er + (dst << 2));
    float4 v;
    v.x = l4.x + r4.x; v.x = v.x > 0.f ? v.x : 0.2f * v.x;
    v.y = l4.y + r4.y; v.y = v.y > 0.f ? v.y : 0.2f * v.y;
    v.z = l4.z + r4.z; v.z = v.z > 0.f ? v.z : 0.2f * v.z;
    v.w = l4.w + r4.w; v.w = v.w > 0.f ? v.w : 0.2f * v.w;
    int p = atomicAdd(&cursor[dst], 1);
    rows[p] = row;
    vsort[p] = v;
}

// ---------------------------------------------------------------------------
// FUSED aggregation (h2-space): 16 nodes/block. Phase A: wave w handles
// nodes 4w..4w+3 sequentially; per edge gather 128B h2 row; accumulate
// per-head weighted sums in h2-space (bond-k in acc, glob-k in accg,
// joint softmax denominator s). Stage agg (128 bf16/node-head) in LDS.
// Phase B: wave w = head w applies the stacked [W2_b;W2_g] (K=128) via
// 16 MFMAs -> out directly. ft is never materialized.
// LDS node-head stride 304B => B-read lanes land 2-way (free, m136).
// ---------------------------------------------------------------------------
#define AGSTR 304
__global__ __launch_bounds__(256) void aggregate_fused_kernel(
    const int* __restrict__ offsets,
    const int* __restrict__ rows,           // (NE) unified h2 row
    const float* __restrict__ vsort,        // (NE,4)
    const unsigned short* __restrict__ h2,  // (NB+NG,64) bf16
    const short* __restrict__ wt2,          // (256,128) bf16 stacked W2
    float* __restrict__ out)                // (NM,256)
{
    __shared__ __attribute__((aligned(16))) char agg_lds[16 * 4 * AGSTR];

    const int w = threadIdx.x >> 6, l = threadIdx.x & 63;
    const int h = l >> 4;        // head group
    const int c = l & 15;        // k-chunk / sample lane
    const int e16 = l & 15;      // metadata lane slot
    const int n0 = blockIdx.x << 4;

    // ---- Phase A: gather 4 nodes (h2-space accumulation) ----
    #pragma unroll
    for (int j = 0; j < 4; ++j) {
        const int n = n0 + 4 * w + j;
        const int start = offsets[n];
        const int deg   = offsets[n + 1] - start;

        f32x4 acc = {}, accg = {};
        float s = 0.f;
        for (int b = 0; b < deg; b += 16) {
            const int rem = min(deg - b, 16);
            int   row_l = 0;
            float v_l   = 0.f;
            if (e16 < rem) {
                row_l = rows[start + b + e16];
                v_l   = vsort[((start + b + e16) << 2) + h];
            }
            int rws[16];
            short4v gv[16];
            #pragma unroll
            for (int e = 0; e < 16; ++e) {
                if (e < rem) {
                    rws[e] = __shfl(row_l, e);
                    gv[e] = *(const short4v*)(h2 + ((size_t)rws[e] << 6) + (c << 2));
                }
            }
            #pragma unroll
            for (int e = 0; e < 16; ++e) {
                if (e < rem) {
                    const float wgt = __expf(__shfl(v_l, (h << 4) + e));
                    s += wgt;
                    const f32x4 fv = {bf2f((unsigned short)gv[e][0]),
                                      bf2f((unsigned short)gv[e][1]),
                                      bf2f((unsigned short)gv[e][2]),
                                      bf2f((unsigned short)gv[e][3])};
                    if (rws[e] >= NB) {
                        accg[0] = fmaf(fv[0], wgt, accg[0]);
                        accg[1] = fmaf(fv[1], wgt, accg[1]);
                        accg[2] = fmaf(fv[2], wgt, accg[2]);
                        accg[3] = fmaf(fv[3], wgt, accg[3]);
                    } else {
                        acc[0] = fmaf(fv[0], wgt, acc[0]);
                        acc[1] = fmaf(fv[1], wgt, acc[1]);
                        acc[2] = fmaf(fv[2], wgt, acc[2]);
                        acc[3] = fmaf(fv[3], wgt, acc[3]);
                    }
                }
            }
        }
        const float inv = (deg > 0) ? 1.f / s : 0.f;
        char* p = agg_lds + ((4 * w + j) * 4 + h) * AGSTR;
        short4v ob, og;
        ob[0] = (short)f2bf(acc[0] * inv);  ob[1] = (short)f2bf(acc[1] * inv);
        ob[2] = (short)f2bf(acc[2] * inv);  ob[3] = (short)f2bf(acc[3] * inv);
        og[0] = (short)f2bf(accg[0] * inv); og[1] = (short)f2bf(accg[1] * inv);
        og[2] = (short)f2bf(accg[2] * inv); og[3] = (short)f2bf(accg[3] * inv);
        *(short4v*)(p + 8 * c)       = ob;   // bond k = 4c..4c+3
        *(short4v*)(p + 128 + 8 * c) = og;   // glob k = 64+4c..+3
    }
    __syncthreads();

    // ---- Phase B: out[node c][64w + d] = agg[c][w][:] @ wt2 block ----
    {
        const int g = l >> 4;   // k-subgroup for fragments
        float* outrow = out + ((size_t)(n0 + c) << 8) + (w << 6);
        #pragma unroll
        for (int it = 0; it < 4; ++it) {
            f32x4 oacc = {};
            #pragma unroll
            for (int st = 0; st < 4; ++st) {
                bf16x8 a = *(const bf16x8*)(wt2 + (((64 * w + 16 * it + c) << 7) + 32 * st + 8 * g));
                bf16x8 bfrag = *(const bf16x8*)(agg_lds + (c * 4 + w) * AGSTR + 64 * st + 16 * g);
                oacc = __builtin_amdgcn_mfma_f32_16x16x32_bf16(a, bfrag, oacc, 0, 0, 0);
            }
            *(f32x4*)(outrow + 16 * it + 4 * g) = oacc;
        }
    }
}

// ---------------------------------------------------------------------------
extern "C" void kernel_launch(void* const* d_in, const int* in_sizes, int n_in,
                              void* d_out, int out_size, void* d_ws, size_t ws_size,
                              hipStream_t stream)
{
    const float* master = (const float*)d_in[0];
    const float* bond   = (const float*)d_in[1];
    const float* glob   = (const float*)d_in[2];
    const float* aW0 = (const float*)d_in[3];
    const float* ab0 = (const float*)d_in[4];
    const float* aW1 = (const float*)d_in[5];
    const float* ab1 = (const float*)d_in[6];
    const float* aW2 = (const float*)d_in[7];
    const float* bW0 = (const float*)d_in[8];
    const float* bb0 = (const float*)d_in[9];
    const float* bW1 = (const float*)d_in[10];
    const float* bb1 = (const float*)d_in[11];
    const float* bW2 = (const float*)d_in[12];
    const float* gW0 = (const float*)d_in[13];
    const float* gb0 = (const float*)d_in[14];
    const float* gW1 = (const float*)d_in[15];
    const float* gb1 = (const float*)d_in[16];
    const float* gW2 = (const float*)d_in[17];
    const float* attn_l = (const float*)d_in[18];
    const float* attn_r = (const float*)d_in[19];
    const int* e1_src = (const int*)d_in[20];
    const int* e1_dst = (const int*)d_in[21];
    const int* e2_src = (const int*)d_in[22];
    const int* e2_dst = (const int*)d_in[23];
    float* out = (float*)d_out;

    // workspace layout
    unsigned short* h2 = (unsigned short*)d_ws;          // (NB+NG)*64 bf16
    float* er   = (float*)(h2 + (size_t)(NB + NG) * 64); // NM*4
    float* el_b = er + (size_t)NM * 4;                   // NB*4
    float* el_g = el_b + (size_t)NB * 4;                 // NG*4
    int* counts  = (int*)(el_g + (size_t)NG * 4);        // NMP
    int* offsets = counts + NMP;                         // NMP
    int* cursor  = offsets + NMP;                        // NMP
    int* rows    = cursor + NMP;                         // NE
    float4* vsort = (float4*)(rows + NE);                // NE float4 (16B aligned)
    int* prefix_inc = (int*)(vsort + NE);                // NMP
    int* blocksums  = prefix_inc + NMP;                  // 512
    float* effR  = (float*)(blocksums + 512);            // 256
    float* effLB = effR + 256;                           // 256
    float* effLG = effLB + 256;                          // 256
    short* wt2 = (short*)(effLG + 256);                  // 32768
    short* wtA = wt2 + 32768;                            // 8192 (W0t+W1t)
    short* wtB = wtA + 8192;
    short* wtG = wtB + 8192;

    hipMemsetAsync(counts, 0, sizeof(int) * NM, stream);

    // weight prep: 6 transposed bf16 matrices + stacked wt2 + 3 eff vectors
    WAll wa;
    wa.e[0] = {aW0, wtA,         64,     0};
    wa.e[1] = {aW1, wtA + 4096,  64,  4096};
    wa.e[2] = {bW0, wtB,         64,  8192};
    wa.e[3] = {bW1, wtB + 4096,  64, 12288};
    wa.e[4] = {gW0, wtG,         64, 16384};
    wa.e[5] = {gW1, wtG + 4096,  64, 20480};
    wprep_all_kernel<<<96, 256, 0, stream>>>(wa);
    wt2prep_kernel<<<128, 256, 0, stream>>>(bW2, gW2, wt2);
    eff_kernel<<<1, 256, 0, stream>>>(aW2, attn_r, effR);
    eff_kernel<<<1, 256, 0, stream>>>(bW2, attn_l, effLB);
    eff_kernel<<<1, 256, 0, stream>>>(gW2, attn_l, effLG);

    mlp2_kernel<<<(NM + 63) / 64, 256, 0, stream>>>(
        master, NM, wtA, ab0, wtA + 4096, ab1, effR, er, nullptr);
    mlp2_kernel<<<(NB + 63) / 64, 256, 0, stream>>>(
        bond, NB, wtB, bb0, wtB + 4096, bb1, effLB, el_b, h2);
    mlp2_kernel<<<(NG + 63) / 64, 256, 0, stream>>>(
        glob, NG, wtG, gb0, wtG + 4096, gb1, effLG, el_g, h2 + (size_t)NB * 64);

    hist_kernel<<<(NE + 255) / 256, 256, 0, stream>>>(e1_dst, e2_dst, counts);
    scan1_kernel<<<SCAN_BLOCKS, 256, 0, stream>>>(counts, prefix_inc, blocksums);
    scan2_kernel<<<1, 512, 0, stream>>>(blocksums);
    scan3_kernel<<<SCAN_BLOCKS + 1, 256, 0, stream>>>(counts, prefix_inc, blocksums,
                                                      offsets, cursor);
    fill_kernel<<<(NE + 255) / 256, 256, 0, stream>>>(e1_src, e1_dst, e2_src, e2_dst,
                                                      er, el_b, el_g,
                                                      cursor, rows, vsort);
    aggregate_fused_kernel<<<NM / 16, 256, 0, stream>>>(offsets, rows,
                                                        (const float*)vsort,
                                                        h2, wt2, out);
}

// Round 15
// 232.968 us; speedup vs baseline: 1.1168x; 1.1117x over previous
//
#include <hip/hip_runtime.h>

#define NM 100000
#define NB 200000
#define NG 5000
#define NE1 400000
#define NE2 100000
#define NE (NE1 + NE2)
#define NMP 100004
#define SCAN_BLOCKS 391  // 391*256 >= NM

typedef __attribute__((ext_vector_type(8))) short bf16x8;
typedef __attribute__((ext_vector_type(4))) short short4v;
typedef __attribute__((ext_vector_type(4))) float f32x4;

__device__ __forceinline__ unsigned short f2bf(float f) {
    unsigned int u = __float_as_uint(f);
    u += 0x7FFFu + ((u >> 16) & 1u);
    return (unsigned short)(u >> 16);
}
__device__ __forceinline__ float bf2f(unsigned short u) {
    return __uint_as_float((unsigned int)u << 16);
}
__device__ __forceinline__ float elu_f(float x) {
    return x > 0.f ? x : __expf(x) - 1.f;
}
// swizzled LDS address: activation tile row j (128B), 16B-slot XOR by (j&7)
__device__ __forceinline__ char* swz(char* base, int j, int byteoff) {
    return base + j * 128 + ((((byteoff >> 4) ^ (j & 7)) << 4) | (byteoff & 15));
}

// ---------------------------------------------------------------------------
// Weight prep: 6 matrices (W0,W1 x atom/bond/glob): Wt[i][k]=bf16(W[k][i]).
// ---------------------------------------------------------------------------
struct WEnt { const float* W; short* o; int I; int off; };
struct WAll { WEnt e[6]; };

__global__ __launch_bounds__(256) void wprep_all_kernel(WAll a)
{
    const int idx = blockIdx.x * 256 + threadIdx.x;  // grid sized exactly (24576)
    #pragma unroll
    for (int j = 5; j >= 0; --j) {
        if (idx >= a.e[j].off) {
            const int local = idx - a.e[j].off;
            const int I = a.e[j].I;
            const int i = local >> 6, k = local & 63;
            a.e[j].o[local] = (short)f2bf(a.e[j].W[k * I + i]);
            break;
        }
    }
}

// stacked transform weight: Wt2[i=0..255][k=0..127], k<64 -> W2_b, else W2_g
__global__ __launch_bounds__(256) void wt2prep_kernel(
    const float* __restrict__ W2b, const float* __restrict__ W2g,
    short* __restrict__ wt2)
{
    const int idx = blockIdx.x * 256 + threadIdx.x;  // 32768 total
    const int i = idx >> 7, k = idx & 127;
    const float v = (k < 64) ? W2b[(k << 8) + i] : W2g[((k - 64) << 8) + i];
    wt2[idx] = (short)f2bf(v);
}

// eff[h][k] = sum_d W2[k][64h+d] * attn[h][d]; 3 matrices in one launch
struct Eff3 { const float* W2[3]; const float* attn[3]; float* eff[3]; };
__global__ __launch_bounds__(256) void eff3_kernel(Eff3 a)
{
    const int b = blockIdx.x;  // 0..2
    const int t = threadIdx.x;
    const int h = t >> 6, k = t & 63;
    const float* wrow = a.W2[b] + (k << 8) + (h << 6);
    const float* arow = a.attn[b] + (h << 6);
    float s = 0.f;
    #pragma unroll 8
    for (int d = 0; d < 64; ++d) s = fmaf(wrow[d], arow[d], s);
    a.eff[b][(h << 6) + k] = s;
}

// ---------------------------------------------------------------------------
// MLP layers 1-2 + score via eff + optional h2 write. Single routed launch
// for bond/glob/master (r14 structure, proven at absmax 0.0117).
// ---------------------------------------------------------------------------
struct MlpArgs {
    const float* x[3]; int N[3];
    const short* W0t[3]; const float* b0[3];
    const short* W1t[3]; const float* b1[3];
    const float* eff[3];
    float* score[3];
    unsigned short* h2o[3];
    int bstart[3];
};

__global__ __launch_bounds__(256, 4) void mlp2_all_kernel(MlpArgs A)
{
    __shared__ __attribute__((aligned(128))) char ldsA[64 * 128];
    __shared__ __attribute__((aligned(128))) char ldsB[64 * 128];

    const int which = (blockIdx.x >= (unsigned)A.bstart[2]) ? 2
                    : (blockIdx.x >= (unsigned)A.bstart[1]) ? 1 : 0;
    const float* x = A.x[which];
    const int N = A.N[which];
    const short* W0t = A.W0t[which];
    const float* b0p = A.b0[which];
    const short* W1t = A.W1t[which];
    const float* b1p = A.b1[which];
    const float* eff = A.eff[which];
    float* score = A.score[which];
    unsigned short* h2p = A.h2o[which];

    const int tid = threadIdx.x;
    const int w = tid >> 6, l = tid & 63;
    const int g = l >> 4, c = l & 15;
    const int r0 = (blockIdx.x - A.bstart[which]) << 6;

    // ---- stage x tile: f32 -> bf16, swizzled [j][k] ----
    {
        const int j = tid >> 2, q = tid & 3;
        const int row = r0 + j;
        bf16x8 o0 = (bf16x8)0, o1 = (bf16x8)0;
        if (row < N) {
            const float4* xp = (const float4*)(x + ((size_t)row << 6) + (q << 4));
            #pragma unroll
            for (int u = 0; u < 2; ++u) {
                float4 v = xp[u];
                o0[u*4+0] = (short)f2bf(v.x); o0[u*4+1] = (short)f2bf(v.y);
                o0[u*4+2] = (short)f2bf(v.z); o0[u*4+3] = (short)f2bf(v.w);
            }
            #pragma unroll
            for (int u = 0; u < 2; ++u) {
                float4 v = xp[u + 2];
                o1[u*4+0] = (short)f2bf(v.x); o1[u*4+1] = (short)f2bf(v.y);
                o1[u*4+2] = (short)f2bf(v.z); o1[u*4+3] = (short)f2bf(v.w);
            }
        }
        *(bf16x8*)swz(ldsA, j, q * 32)      = o0;
        *(bf16x8*)swz(ldsA, j, q * 32 + 16) = o1;
    }
    __syncthreads();

    // ---- layers 1 and 2 (64->64, ELU) ----
    char* src = ldsA;
    char* dst = ldsB;
    #pragma unroll
    for (int layer = 0; layer < 2; ++layer) {
        const short* Wt = layer ? W1t : W0t;
        const float* bb = layer ? b1p : b0p;
        f32x4 acc[4] = {};
        #pragma unroll
        for (int step = 0; step < 2; ++step) {
            bf16x8 a = *(const bf16x8*)(Wt + (((16 * w + c) << 6) + 32 * step + 8 * g));
            #pragma unroll
            for (int t = 0; t < 4; ++t) {
                const int j = 16 * t + c;
                bf16x8 b = *(const bf16x8*)swz(src, j, 64 * step + 16 * g);
                acc[t] = __builtin_amdgcn_mfma_f32_16x16x32_bf16(a, b, acc[t], 0, 0, 0);
            }
        }
        const int i0 = 16 * w + 4 * g;
        const float4 bias = *(const float4*)(bb + i0);
        #pragma unroll
        for (int t = 0; t < 4; ++t) {
            const int j = 16 * t + c;
            short4v o;
            o[0] = (short)f2bf(elu_f(acc[t][0] + bias.x));
            o[1] = (short)f2bf(elu_f(acc[t][1] + bias.y));
            o[2] = (short)f2bf(elu_f(acc[t][2] + bias.z));
            o[3] = (short)f2bf(elu_f(acc[t][3] + bias.w));
            *(short4v*)swz(dst, j, 32 * w + 8 * g) = o;
        }
        __syncthreads();
        char* tmp = src; src = dst; dst = tmp;
    }

    // ---- epilogue 1: score[row,h] = h2[row] . eff[h] ----
    {
        const int j = tid >> 2, h = tid & 3;
        const int row = r0 + j;
        float s = 0.f;
        #pragma unroll
        for (int c8 = 0; c8 < 8; ++c8) {
            bf16x8 v = *(const bf16x8*)swz(src, j, c8 * 16);
            const float4 e0 = *(const float4*)(eff + (h << 6) + (c8 << 3));
            const float4 e1 = *(const float4*)(eff + (h << 6) + (c8 << 3) + 4);
            s += bf2f((unsigned short)v[0]) * e0.x + bf2f((unsigned short)v[1]) * e0.y
               + bf2f((unsigned short)v[2]) * e0.z + bf2f((unsigned short)v[3]) * e0.w
               + bf2f((unsigned short)v[4]) * e1.x + bf2f((unsigned short)v[5]) * e1.y
               + bf2f((unsigned short)v[6]) * e1.z + bf2f((unsigned short)v[7]) * e1.w;
        }
        if (row < N) score[(row << 2) + h] = s;
    }

    // ---- epilogue 2: h2 write-out (bf16 linear (N,64)) ----
    if (h2p) {
        const int j = tid >> 2, q = tid & 3;
        const int row = r0 + j;
        if (row < N) {
            bf16x8 v0 = *(const bf16x8*)swz(src, j, q * 32);
            bf16x8 v1 = *(const bf16x8*)swz(src, j, q * 32 + 16);
            unsigned short* p = h2p + ((size_t)row << 6) + (q << 4);
            *(bf16x8*)p       = v0;
            *(bf16x8*)(p + 8) = v1;
        }
    }
}

// ---------------------------------------------------------------------------
// CSR build: histogram -> 3-phase parallel scan -> fill
// ---------------------------------------------------------------------------
__global__ void hist_kernel(const int* __restrict__ e1_dst,
                            const int* __restrict__ e2_dst,
                            int* __restrict__ counts)
{
    int i = blockIdx.x * blockDim.x + threadIdx.x;
    if (i < NE1) atomicAdd(&counts[e1_dst[i]], 1);
    else if (i < NE) atomicAdd(&counts[e2_dst[i - NE1]], 1);
}

__global__ __launch_bounds__(256) void scan1_kernel(
    const int* __restrict__ counts,
    int* __restrict__ prefix_inc,
    int* __restrict__ blocksums)
{
    const int i = blockIdx.x * 256 + threadIdx.x;
    const int lane = threadIdx.x & 63, wv = threadIdx.x >> 6;
    int v = (i < NM) ? counts[i] : 0;
    int x = v;
    #pragma unroll
    for (int o = 1; o < 64; o <<= 1) {
        int u = __shfl_up(x, o);
        if (lane >= o) x += u;
    }
    __shared__ int wsum[4];
    if (lane == 63) wsum[wv] = x;
    __syncthreads();
    int add = 0;
    #pragma unroll
    for (int k = 0; k < 3; ++k) add += (k < wv) ? wsum[k] : 0;
    x += add;
    if (i < NM) prefix_inc[i] = x;
    if (threadIdx.x == 255) blocksums[blockIdx.x] = x;
}

__global__ __launch_bounds__(512) void scan2_kernel(int* __restrict__ blocksums)
{
    const int t = threadIdx.x;
    const int lane = t & 63, wv = t >> 6;
    int v = (t < SCAN_BLOCKS) ? blocksums[t] : 0;
    int x = v;
    #pragma unroll
    for (int o = 1; o < 64; o <<= 1) {
        int u = __shfl_up(x, o);
        if (lane >= o) x += u;
    }
    __shared__ int wsum[8];
    if (lane == 63) wsum[wv] = x;
    __syncthreads();
    int add = 0;
    #pragma unroll
    for (int k = 0; k < 7; ++k) add += (k < wv) ? wsum[k] : 0;
    x += add;
    if (t < SCAN_BLOCKS) blocksums[t] = x - v;  // exclusive
}

// scan3: offsets, bond cursor (front), glob cursor2 (back = next offset)
__global__ __launch_bounds__(256) void scan3_kernel(
    const int* __restrict__ counts,
    const int* __restrict__ prefix_inc,
    const int* __restrict__ blocksums,
    int* __restrict__ offsets,
    int* __restrict__ cursor,
    int* __restrict__ cursor2)
{
    const int i = blockIdx.x * 256 + threadIdx.x;
    if (i > NM) return;
    if (i == NM) { offsets[NM] = NE; return; }
    const int off = prefix_inc[i] - counts[i] + blocksums[blockIdx.x];
    offsets[i] = off;
    cursor[i]  = off;
    cursor2[i] = off + counts[i];   // segment end; glob edges fill downward
}

// fill: bond edges -> front slots (cursor++), glob -> back slots (cursor2--).
// Stores UNIFIED h2 row index and PRE-EXPONENTIATED weights (4 heads).
__global__ void fill_kernel(const int* __restrict__ e1_src,
                            const int* __restrict__ e1_dst,
                            const int* __restrict__ e2_src,
                            const int* __restrict__ e2_dst,
                            const float* __restrict__ er,
                            const float* __restrict__ el_b,
                            const float* __restrict__ el_g,
                            int* __restrict__ cursor,
                            int* __restrict__ cursor2,
                            int* __restrict__ rows,
                            float4* __restrict__ expv)
{
    int i = blockIdx.x * blockDim.x + threadIdx.x;
    if (i >= NE) return;
    int dst, src, row, isglob;
    const float* el;
    if (i < NE1) { src = e1_src[i]; dst = e1_dst[i]; row = src;      el = el_b; isglob = 0; }
    else { int j = i - NE1; src = e2_src[j]; dst = e2_dst[j]; row = NB + src; el = el_g; isglob = 1; }
    const float4 l4 = *(const float4*)(el + (src << 2));
    const float4 r4 = *(const float4*)(er + (dst << 2));
    float4 v;
    v.x = l4.x + r4.x; v.x = v.x > 0.f ? v.x : 0.2f * v.x;
    v.y = l4.y + r4.y; v.y = v.y > 0.f ? v.y : 0.2f * v.y;
    v.z = l4.z + r4.z; v.z = v.z > 0.f ? v.z : 0.2f * v.z;
    v.w = l4.w + r4.w; v.w = v.w > 0.f ? v.w : 0.2f * v.w;
    float4 ev;
    ev.x = __expf(v.x); ev.y = __expf(v.y); ev.z = __expf(v.z); ev.w = __expf(v.w);
    int p = isglob ? (atomicSub(&cursor2[dst], 1) - 1)
                   : atomicAdd(&cursor[dst], 1);
    rows[p] = row;
    expv[p] = ev;
}

// ---------------------------------------------------------------------------
// FUSED aggregation v2: 1024-thr block = 16 waves = 16 nodes (ONE node per
// wave -> full gather concurrency, r7 lesson). Per edge: 1 shfl + 4 fma + add
// (exp precomputed in fill; bond/glob segments sorted -> branch-free loops).
// Phase B: 16 waves = (it,h) pairs, 4 MFMAs each, stacked [W2_b;W2_g] K=128.
// LDS rows ordered (h*16+node), stride 304B (19 x 16B, odd -> Phase B B-frag
// reads spread all bank groups).
// ---------------------------------------------------------------------------
#define AGSTR 304
__global__ __launch_bounds__(1024) void aggregate_fused_kernel(
    const int* __restrict__ offsets,
    const int* __restrict__ split,          // final cursor2 = first glob slot
    const int* __restrict__ rows,           // (NE) unified h2 row
    const float* __restrict__ expv,         // (NE,4) pre-exponentiated
    const unsigned short* __restrict__ h2,  // (NB+NG,64) bf16
    const short* __restrict__ wt2,          // (256,128) bf16 stacked W2
    float* __restrict__ out)                // (NM,256)
{
    __shared__ __attribute__((aligned(16))) char agg_lds[64 * AGSTR];

    const int tid = threadIdx.x;
    const int wv = tid >> 6, l = tid & 63;
    const int h = l >> 4, c = l & 15;
    const int n0 = blockIdx.x << 4;

    // ---- Phase A: wave wv aggregates node n0+wv in h2-space ----
    {
        const int n = n0 + wv;
        const int start = offsets[n];
        const int sp    = split[n];
        const int end   = offsets[n + 1];

        f32x4 acc = {}, accg = {};
        float s = 0.f;

        // bond edges [start, sp)
        for (int b = start; b < sp; b += 8) {
            const int rem = min(sp - b, 8);
            int row_l = 0; float v_l = 0.f;
            if (c < rem) { row_l = rows[b + c]; v_l = expv[((b + c) << 2) + h]; }
            short4v gv[8];
            #pragma unroll
            for (int e = 0; e < 8; ++e) {
                if (e < rem)
                    gv[e] = *(const short4v*)(h2 + ((size_t)__shfl(row_l, e) << 6) + (c << 2));
            }
            #pragma unroll
            for (int e = 0; e < 8; ++e) {
                if (e < rem) {
                    const float wgt = __shfl(v_l, (h << 4) + e);
                    s += wgt;
                    acc[0] = fmaf(bf2f((unsigned short)gv[e][0]), wgt, acc[0]);
                    acc[1] = fmaf(bf2f((unsigned short)gv[e][1]), wgt, acc[1]);
                    acc[2] = fmaf(bf2f((unsigned short)gv[e][2]), wgt, acc[2]);
                    acc[3] = fmaf(bf2f((unsigned short)gv[e][3]), wgt, acc[3]);
                }
            }
        }
        // glob edges [sp, end)
        for (int b = sp; b < end; b += 8) {
            const int rem = min(end - b, 8);
            int row_l = 0; float v_l = 0.f;
            if (c < rem) { row_l = rows[b + c]; v_l = expv[((b + c) << 2) + h]; }
            short4v gv[8];
            #pragma unroll
            for (int e = 0; e < 8; ++e) {
                if (e < rem)
                    gv[e] = *(const short4v*)(h2 + ((size_t)__shfl(row_l, e) << 6) + (c << 2));
            }
            #pragma unroll
            for (int e = 0; e < 8; ++e) {
                if (e < rem) {
                    const float wgt = __shfl(v_l, (h << 4) + e);
                    s += wgt;
                    accg[0] = fmaf(bf2f((unsigned short)gv[e][0]), wgt, accg[0]);
                    accg[1] = fmaf(bf2f((unsigned short)gv[e][1]), wgt, accg[1]);
                    accg[2] = fmaf(bf2f((unsigned short)gv[e][2]), wgt, accg[2]);
                    accg[3] = fmaf(bf2f((unsigned short)gv[e][3]), wgt, accg[3]);
                }
            }
        }

        const float inv = (end > start) ? 1.f / s : 0.f;
        char* p = agg_lds + (h * 16 + wv) * AGSTR;
        short4v ob, og;
        ob[0] = (short)f2bf(acc[0] * inv);  ob[1] = (short)f2bf(acc[1] * inv);
        ob[2] = (short)f2bf(acc[2] * inv);  ob[3] = (short)f2bf(acc[3] * inv);
        og[0] = (short)f2bf(accg[0] * inv); og[1] = (short)f2bf(accg[1] * inv);
        og[2] = (short)f2bf(accg[2] * inv); og[3] = (short)f2bf(accg[3] * inv);
        *(short4v*)(p + 8 * c)       = ob;   // bond k = 4c..4c+3
        *(short4v*)(p + 128 + 8 * c) = og;   // glob k = 64+4c..+3
    }
    __syncthreads();

    // ---- Phase B: wave wv -> (it = wv>>2, head hb = wv&3), 4 MFMAs ----
    {
        const int it = wv >> 2, hb = wv & 3;
        const int g = l >> 4;
        f32x4 oacc = {};
        #pragma unroll
        for (int st = 0; st < 4; ++st) {
            bf16x8 a = *(const bf16x8*)(wt2 + ((((hb << 6) + (it << 4) + c) << 7) + 32 * st + 8 * g));
            bf16x8 bfrag = *(const bf16x8*)(agg_lds + (hb * 16 + c) * AGSTR + 64 * st + 16 * g);
            oacc = __builtin_amdgcn_mfma_f32_16x16x32_bf16(a, bfrag, oacc, 0, 0, 0);
        }
        *(f32x4*)(out + ((size_t)(n0 + c) << 8) + (hb << 6) + (it << 4) + (g << 2)) = oacc;
    }
}

// ---------------------------------------------------------------------------
extern "C" void kernel_launch(void* const* d_in, const int* in_sizes, int n_in,
                              void* d_out, int out_size, void* d_ws, size_t ws_size,
                              hipStream_t stream)
{
    const float* master = (const float*)d_in[0];
    const float* bond   = (const float*)d_in[1];
    const float* glob   = (const float*)d_in[2];
    const float* aW0 = (const float*)d_in[3];
    const float* ab0 = (const float*)d_in[4];
    const float* aW1 = (const float*)d_in[5];
    const float* ab1 = (const float*)d_in[6];
    const float* aW2 = (const float*)d_in[7];
    const float* bW0 = (const float*)d_in[8];
    const float* bb0 = (const float*)d_in[9];
    const float* bW1 = (const float*)d_in[10];
    const float* bb1 = (const float*)d_in[11];
    const float* bW2 = (const float*)d_in[12];
    const float* gW0 = (const float*)d_in[13];
    const float* gb0 = (const float*)d_in[14];
    const float* gW1 = (const float*)d_in[15];
    const float* gb1 = (const float*)d_in[16];
    const float* gW2 = (const float*)d_in[17];
    const float* attn_l = (const float*)d_in[18];
    const float* attn_r = (const float*)d_in[19];
    const int* e1_src = (const int*)d_in[20];
    const int* e1_dst = (const int*)d_in[21];
    const int* e2_src = (const int*)d_in[22];
    const int* e2_dst = (const int*)d_in[23];
    float* out = (float*)d_out;

    // workspace layout
    unsigned short* h2 = (unsigned short*)d_ws;          // (NB+NG)*64 bf16
    float* er   = (float*)(h2 + (size_t)(NB + NG) * 64); // NM*4
    float* el_b = er + (size_t)NM * 4;                   // NB*4
    float* el_g = el_b + (size_t)NB * 4;                 // NG*4
    int* counts  = (int*)(el_g + (size_t)NG * 4);        // NMP
    int* offsets = counts + NMP;                         // NMP
    int* cursor  = offsets + NMP;                        // NMP
    int* cursor2 = cursor + NMP;                         // NMP
    int* rows    = cursor2 + NMP;                        // NE
    float4* expv = (float4*)(rows + NE);                 // NE float4
    int* prefix_inc = (int*)(expv + NE);                 // NMP
    int* blocksums  = prefix_inc + NMP;                  // 512
    float* effR  = (float*)(blocksums + 512);            // 256
    float* effLB = effR + 256;                           // 256
    float* effLG = effLB + 256;                          // 256
    short* wt2 = (short*)(effLG + 256);                  // 32768
    short* wtA = wt2 + 32768;                            // 8192 (W0t+W1t)
    short* wtB = wtA + 8192;
    short* wtG = wtB + 8192;

    hipMemsetAsync(counts, 0, sizeof(int) * NM, stream);

    // weight prep
    WAll wa;
    wa.e[0] = {aW0, wtA,         64,     0};
    wa.e[1] = {aW1, wtA + 4096,  64,  4096};
    wa.e[2] = {bW0, wtB,         64,  8192};
    wa.e[3] = {bW1, wtB + 4096,  64, 12288};
    wa.e[4] = {gW0, wtG,         64, 16384};
    wa.e[5] = {gW1, wtG + 4096,  64, 20480};
    wprep_all_kernel<<<96, 256, 0, stream>>>(wa);
    wt2prep_kernel<<<128, 256, 0, stream>>>(bW2, gW2, wt2);
    Eff3 ef;
    ef.W2[0] = aW2; ef.attn[0] = attn_r; ef.eff[0] = effR;
    ef.W2[1] = bW2; ef.attn[1] = attn_l; ef.eff[1] = effLB;
    ef.W2[2] = gW2; ef.attn[2] = attn_l; ef.eff[2] = effLG;
    eff3_kernel<<<3, 256, 0, stream>>>(ef);

    // merged MLP launch: bond (3125) | glob (79) | master (1563)
    MlpArgs ma;
    ma.x[0] = bond;   ma.N[0] = NB; ma.W0t[0] = wtB; ma.b0[0] = bb0;
    ma.W1t[0] = wtB + 4096; ma.b1[0] = bb1; ma.eff[0] = effLB;
    ma.score[0] = el_b; ma.h2o[0] = h2;
    ma.x[1] = glob;   ma.N[1] = NG; ma.W0t[1] = wtG; ma.b0[1] = gb0;
    ma.W1t[1] = wtG + 4096; ma.b1[1] = gb1; ma.eff[1] = effLG;
    ma.score[1] = el_g; ma.h2o[1] = h2 + (size_t)NB * 64;
    ma.x[2] = master; ma.N[2] = NM; ma.W0t[2] = wtA; ma.b0[2] = ab0;
    ma.W1t[2] = wtA + 4096; ma.b1[2] = ab1; ma.eff[2] = effR;
    ma.score[2] = er;   ma.h2o[2] = nullptr;
    ma.bstart[0] = 0;
    ma.bstart[1] = (NB + 63) / 64;                       // 3125
    ma.bstart[2] = ma.bstart[1] + (NG + 63) / 64;        // 3204
    const int nblk = ma.bstart[2] + (NM + 63) / 64;      // 4767
    mlp2_all_kernel<<<nblk, 256, 0, stream>>>(ma);

    hist_kernel<<<(NE + 255) / 256, 256, 0, stream>>>(e1_dst, e2_dst, counts);
    scan1_kernel<<<SCAN_BLOCKS, 256, 0, stream>>>(counts, prefix_inc, blocksums);
    scan2_kernel<<<1, 512, 0, stream>>>(blocksums);
    scan3_kernel<<<SCAN_BLOCKS + 1, 256, 0, stream>>>(counts, prefix_inc, blocksums,
                                                      offsets, cursor, cursor2);
    fill_kernel<<<(NE + 255) / 256, 256, 0, stream>>>(e1_src, e1_dst, e2_src, e2_dst,
                                                      er, el_b, el_g,
                                                      cursor, cursor2, rows, expv);
    aggregate_fused_kernel<<<NM / 16, 1024, 0, stream>>>(offsets, cursor2, rows,
                                                         (const float*)expv,
                                                         h2, wt2, out);
}

// Round 16
// 227.735 us; speedup vs baseline: 1.1425x; 1.0230x over previous
//
#include <hip/hip_runtime.h>

#define NM 100000
#define NB 200000
#define NG 5000
#define NE1 400000
#define NE2 100000
#define NE (NE1 + NE2)
#define NMP 100004
#define SCAN_BLOCKS 391  // 391*256 >= NM

typedef __attribute__((ext_vector_type(8))) short bf16x8;
typedef __attribute__((ext_vector_type(4))) short short4v;
typedef __attribute__((ext_vector_type(4))) float f32x4;

__device__ __forceinline__ unsigned short f2bf(float f) {
    unsigned int u = __float_as_uint(f);
    u += 0x7FFFu + ((u >> 16) & 1u);
    return (unsigned short)(u >> 16);
}
__device__ __forceinline__ float bf2f(unsigned short u) {
    return __uint_as_float((unsigned int)u << 16);
}
__device__ __forceinline__ float elu_f(float x) {
    return x > 0.f ? x : __expf(x) - 1.f;
}
// swizzled LDS address: activation tile row j (128B), 16B-slot XOR by (j&7)
__device__ __forceinline__ char* swz(char* base, int j, int byteoff) {
    return base + j * 128 + ((((byteoff >> 4) ^ (j & 7)) << 4) | (byteoff & 15));
}

// ---------------------------------------------------------------------------
// Weight prep: 6 matrices (W0,W1 x atom/bond/glob): Wt[i][k]=bf16(W[k][i]).
// ---------------------------------------------------------------------------
struct WEnt { const float* W; short* o; int I; int off; };
struct WAll { WEnt e[6]; };

__global__ __launch_bounds__(256) void wprep_all_kernel(WAll a)
{
    const int idx = blockIdx.x * 256 + threadIdx.x;  // grid sized exactly (24576)
    #pragma unroll
    for (int j = 5; j >= 0; --j) {
        if (idx >= a.e[j].off) {
            const int local = idx - a.e[j].off;
            const int I = a.e[j].I;
            const int i = local >> 6, k = local & 63;
            a.e[j].o[local] = (short)f2bf(a.e[j].W[k * I + i]);
            break;
        }
    }
}

// stacked transform weight: Wt2[i=0..255][k=0..127], k<64 -> W2_b, else W2_g
__global__ __launch_bounds__(256) void wt2prep_kernel(
    const float* __restrict__ W2b, const float* __restrict__ W2g,
    short* __restrict__ wt2)
{
    const int idx = blockIdx.x * 256 + threadIdx.x;  // 32768 total
    const int i = idx >> 7, k = idx & 127;
    const float v = (k < 64) ? W2b[(k << 8) + i] : W2g[((k - 64) << 8) + i];
    wt2[idx] = (short)f2bf(v);
}

// eff[h][k] = sum_d W2[k][64h+d] * attn[h][d]; 3 matrices in one launch
struct Eff3 { const float* W2[3]; const float* attn[3]; float* eff[3]; };
__global__ __launch_bounds__(256) void eff3_kernel(Eff3 a)
{
    const int b = blockIdx.x;  // 0..2
    const int t = threadIdx.x;
    const int h = t >> 6, k = t & 63;
    const float* wrow = a.W2[b] + (k << 8) + (h << 6);
    const float* arow = a.attn[b] + (h << 6);
    float s = 0.f;
    #pragma unroll 8
    for (int d = 0; d < 64; ++d) s = fmaf(wrow[d], arow[d], s);
    a.eff[b][(h << 6) + k] = s;
}

// ---------------------------------------------------------------------------
// MLP layers 1-2 + score via eff + optional h2 write. Single routed launch.
// ---------------------------------------------------------------------------
struct MlpArgs {
    const float* x[3]; int N[3];
    const short* W0t[3]; const float* b0[3];
    const short* W1t[3]; const float* b1[3];
    const float* eff[3];
    float* score[3];
    unsigned short* h2o[3];
    int bstart[3];
};

__global__ __launch_bounds__(256, 4) void mlp2_all_kernel(MlpArgs A)
{
    __shared__ __attribute__((aligned(128))) char ldsA[64 * 128];
    __shared__ __attribute__((aligned(128))) char ldsB[64 * 128];

    const int which = (blockIdx.x >= (unsigned)A.bstart[2]) ? 2
                    : (blockIdx.x >= (unsigned)A.bstart[1]) ? 1 : 0;
    const float* x = A.x[which];
    const int N = A.N[which];
    const short* W0t = A.W0t[which];
    const float* b0p = A.b0[which];
    const short* W1t = A.W1t[which];
    const float* b1p = A.b1[which];
    const float* eff = A.eff[which];
    float* score = A.score[which];
    unsigned short* h2p = A.h2o[which];

    const int tid = threadIdx.x;
    const int w = tid >> 6, l = tid & 63;
    const int g = l >> 4, c = l & 15;
    const int r0 = (blockIdx.x - A.bstart[which]) << 6;

    // ---- stage x tile: f32 -> bf16, swizzled [j][k] ----
    {
        const int j = tid >> 2, q = tid & 3;
        const int row = r0 + j;
        bf16x8 o0 = (bf16x8)0, o1 = (bf16x8)0;
        if (row < N) {
            const float4* xp = (const float4*)(x + ((size_t)row << 6) + (q << 4));
            #pragma unroll
            for (int u = 0; u < 2; ++u) {
                float4 v = xp[u];
                o0[u*4+0] = (short)f2bf(v.x); o0[u*4+1] = (short)f2bf(v.y);
                o0[u*4+2] = (short)f2bf(v.z); o0[u*4+3] = (short)f2bf(v.w);
            }
            #pragma unroll
            for (int u = 0; u < 2; ++u) {
                float4 v = xp[u + 2];
                o1[u*4+0] = (short)f2bf(v.x); o1[u*4+1] = (short)f2bf(v.y);
                o1[u*4+2] = (short)f2bf(v.z); o1[u*4+3] = (short)f2bf(v.w);
            }
        }
        *(bf16x8*)swz(ldsA, j, q * 32)      = o0;
        *(bf16x8*)swz(ldsA, j, q * 32 + 16) = o1;
    }
    __syncthreads();

    // ---- layers 1 and 2 (64->64, ELU) ----
    char* src = ldsA;
    char* dst = ldsB;
    #pragma unroll
    for (int layer = 0; layer < 2; ++layer) {
        const short* Wt = layer ? W1t : W0t;
        const float* bb = layer ? b1p : b0p;
        f32x4 acc[4] = {};
        #pragma unroll
        for (int step = 0; step < 2; ++step) {
            bf16x8 a = *(const bf16x8*)(Wt + (((16 * w + c) << 6) + 32 * step + 8 * g));
            #pragma unroll
            for (int t = 0; t < 4; ++t) {
                const int j = 16 * t + c;
                bf16x8 b = *(const bf16x8*)swz(src, j, 64 * step + 16 * g);
                acc[t] = __builtin_amdgcn_mfma_f32_16x16x32_bf16(a, b, acc[t], 0, 0, 0);
            }
        }
        const int i0 = 16 * w + 4 * g;
        const float4 bias = *(const float4*)(bb + i0);
        #pragma unroll
        for (int t = 0; t < 4; ++t) {
            const int j = 16 * t + c;
            short4v o;
            o[0] = (short)f2bf(elu_f(acc[t][0] + bias.x));
            o[1] = (short)f2bf(elu_f(acc[t][1] + bias.y));
            o[2] = (short)f2bf(elu_f(acc[t][2] + bias.z));
            o[3] = (short)f2bf(elu_f(acc[t][3] + bias.w));
            *(short4v*)swz(dst, j, 32 * w + 8 * g) = o;
        }
        __syncthreads();
        char* tmp = src; src = dst; dst = tmp;
    }

    // ---- epilogue 1: score[row,h] = h2[row] . eff[h] ----
    {
        const int j = tid >> 2, h = tid & 3;
        const int row = r0 + j;
        float s = 0.f;
        #pragma unroll
        for (int c8 = 0; c8 < 8; ++c8) {
            bf16x8 v = *(const bf16x8*)swz(src, j, c8 * 16);
            const float4 e0 = *(const float4*)(eff + (h << 6) + (c8 << 3));
            const float4 e1 = *(const float4*)(eff + (h << 6) + (c8 << 3) + 4);
            s += bf2f((unsigned short)v[0]) * e0.x + bf2f((unsigned short)v[1]) * e0.y
               + bf2f((unsigned short)v[2]) * e0.z + bf2f((unsigned short)v[3]) * e0.w
               + bf2f((unsigned short)v[4]) * e1.x + bf2f((unsigned short)v[5]) * e1.y
               + bf2f((unsigned short)v[6]) * e1.z + bf2f((unsigned short)v[7]) * e1.w;
        }
        if (row < N) score[(row << 2) + h] = s;
    }

    // ---- epilogue 2: h2 write-out (bf16 linear (N,64)) ----
    if (h2p) {
        const int j = tid >> 2, q = tid & 3;
        const int row = r0 + j;
        if (row < N) {
            bf16x8 v0 = *(const bf16x8*)swz(src, j, q * 32);
            bf16x8 v1 = *(const bf16x8*)swz(src, j, q * 32 + 16);
            unsigned short* p = h2p + ((size_t)row << 6) + (q << 4);
            *(bf16x8*)p       = v0;
            *(bf16x8*)(p + 8) = v1;
        }
    }
}

// ---------------------------------------------------------------------------
// CSR build: histogram -> 3-phase parallel scan -> fill
// ---------------------------------------------------------------------------
__global__ void hist_kernel(const int* __restrict__ e1_dst,
                            const int* __restrict__ e2_dst,
                            int* __restrict__ counts)
{
    int i = blockIdx.x * blockDim.x + threadIdx.x;
    if (i < NE1) atomicAdd(&counts[e1_dst[i]], 1);
    else if (i < NE) atomicAdd(&counts[e2_dst[i - NE1]], 1);
}

__global__ __launch_bounds__(256) void scan1_kernel(
    const int* __restrict__ counts,
    int* __restrict__ prefix_inc,
    int* __restrict__ blocksums)
{
    const int i = blockIdx.x * 256 + threadIdx.x;
    const int lane = threadIdx.x & 63, wv = threadIdx.x >> 6;
    int v = (i < NM) ? counts[i] : 0;
    int x = v;
    #pragma unroll
    for (int o = 1; o < 64; o <<= 1) {
        int u = __shfl_up(x, o);
        if (lane >= o) x += u;
    }
    __shared__ int wsum[4];
    if (lane == 63) wsum[wv] = x;
    __syncthreads();
    int add = 0;
    #pragma unroll
    for (int k = 0; k < 3; ++k) add += (k < wv) ? wsum[k] : 0;
    x += add;
    if (i < NM) prefix_inc[i] = x;
    if (threadIdx.x == 255) blocksums[blockIdx.x] = x;
}

__global__ __launch_bounds__(512) void scan2_kernel(int* __restrict__ blocksums)
{
    const int t = threadIdx.x;
    const int lane = t & 63, wv = t >> 6;
    int v = (t < SCAN_BLOCKS) ? blocksums[t] : 0;
    int x = v;
    #pragma unroll
    for (int o = 1; o < 64; o <<= 1) {
        int u = __shfl_up(x, o);
        if (lane >= o) x += u;
    }
    __shared__ int wsum[8];
    if (lane == 63) wsum[wv] = x;
    __syncthreads();
    int add = 0;
    #pragma unroll
    for (int k = 0; k < 7; ++k) add += (k < wv) ? wsum[k] : 0;
    x += add;
    if (t < SCAN_BLOCKS) blocksums[t] = x - v;  // exclusive
}

// scan3: offsets, bond cursor (front), glob cursor2 (back = segment end)
__global__ __launch_bounds__(256) void scan3_kernel(
    const int* __restrict__ counts,
    const int* __restrict__ prefix_inc,
    const int* __restrict__ blocksums,
    int* __restrict__ offsets,
    int* __restrict__ cursor,
    int* __restrict__ cursor2)
{
    const int i = blockIdx.x * 256 + threadIdx.x;
    if (i > NM) return;
    if (i == NM) { offsets[NM] = NE; return; }
    const int off = prefix_inc[i] - counts[i] + blocksums[blockIdx.x];
    offsets[i] = off;
    cursor[i]  = off;
    cursor2[i] = off + counts[i];   // glob edges fill downward from end
}

// fill: bond edges -> front slots (cursor++), glob -> back slots (cursor2--).
// Stores UNIFIED h2 row index and PRE-EXPONENTIATED weights (4 heads).
__global__ void fill_kernel(const int* __restrict__ e1_src,
                            const int* __restrict__ e1_dst,
                            const int* __restrict__ e2_src,
                            const int* __restrict__ e2_dst,
                            const float* __restrict__ er,
                            const float* __restrict__ el_b,
                            const float* __restrict__ el_g,
                            int* __restrict__ cursor,
                            int* __restrict__ cursor2,
                            int* __restrict__ rows,
                            float4* __restrict__ expv)
{
    int i = blockIdx.x * blockDim.x + threadIdx.x;
    if (i >= NE) return;
    int dst, src, row, isglob;
    const float* el;
    if (i < NE1) { src = e1_src[i]; dst = e1_dst[i]; row = src;      el = el_b; isglob = 0; }
    else { int j = i - NE1; src = e2_src[j]; dst = e2_dst[j]; row = NB + src; el = el_g; isglob = 1; }
    const float4 l4 = *(const float4*)(el + (src << 2));
    const float4 r4 = *(const float4*)(er + (dst << 2));
    float4 v;
    v.x = l4.x + r4.x; v.x = v.x > 0.f ? v.x : 0.2f * v.x;
    v.y = l4.y + r4.y; v.y = v.y > 0.f ? v.y : 0.2f * v.y;
    v.z = l4.z + r4.z; v.z = v.z > 0.f ? v.z : 0.2f * v.z;
    v.w = l4.w + r4.w; v.w = v.w > 0.f ? v.w : 0.2f * v.w;
    float4 ev;
    ev.x = __expf(v.x); ev.y = __expf(v.y); ev.z = __expf(v.z); ev.w = __expf(v.w);
    int p = isglob ? (atomicSub(&cursor2[dst], 1) - 1)
                   : atomicAdd(&cursor[dst], 1);
    rows[p] = row;
    expv[p] = ev;
}

// ---------------------------------------------------------------------------
// FUSED aggregation v3: 256-thr block = 4 waves x 4 nodes = 16 nodes.
// Lane (h = l>>4, c = l&15) owns (head h, k-chunk 4c..4c+3) exclusively:
// NO shfl, NO cross-lane reduce. Per edge: direct loads wgt=expv[slot*4+h]
// (L1 broadcast) + row=rows[slot] (uniform), 1 gather, 4 fma, 1 add.
// Unroll-4 with clamp-and-zero tail keeps 4 gathers in flight, no exec
// masking (r15 lesson: shfl+mask overhead was ~40us of pure VALU).
// Phase B: wave w = head w applies stacked [W2_b;W2_g] via 16 MFMAs.
// ---------------------------------------------------------------------------
#define AGSTR 304
__global__ __launch_bounds__(256) void aggregate_fused_kernel(
    const int* __restrict__ offsets,
    const int* __restrict__ split,          // final cursor2 = first glob slot
    const int* __restrict__ rows,           // (NE) unified h2 row
    const float* __restrict__ expv,         // (NE,4) pre-exponentiated
    const unsigned short* __restrict__ h2,  // (NB+NG,64) bf16
    const short* __restrict__ wt2,          // (256,128) bf16 stacked W2
    float* __restrict__ out)                // (NM,256)
{
    __shared__ __attribute__((aligned(16))) char agg_lds[64 * AGSTR];

    const int tid = threadIdx.x;
    const int w = tid >> 6, l = tid & 63;
    const int h = l >> 4, c = l & 15;
    const int n0 = blockIdx.x << 4;

    // ---- Phase A: wave w aggregates nodes n0+4w..n0+4w+3 in h2-space ----
    #pragma unroll
    for (int j = 0; j < 4; ++j) {
        const int ln = 4 * w + j;          // local node 0..15
        const int n  = n0 + ln;
        const int start = offsets[n];
        const int sp    = split[n];
        const int end   = offsets[n + 1];

        f32x4 acc = {}, accg = {};
        float s = 0.f;

        // bond edges [start, sp)
        for (int b = start; b < sp; b += 4) {
            float  wg[4];
            short4v gv[4];
            #pragma unroll
            for (int i = 0; i < 4; ++i) {
                const int sl = b + i;
                const int sc = sl < sp ? sl : sp - 1;
                const float wv = expv[(sc << 2) + h];
                wg[i] = (sl < sp) ? wv : 0.f;
                const int row = rows[sc];
                gv[i] = *(const short4v*)(h2 + ((size_t)row << 6) + (c << 2));
            }
            #pragma unroll
            for (int i = 0; i < 4; ++i) {
                s += wg[i];
                acc[0] = fmaf(bf2f((unsigned short)gv[i][0]), wg[i], acc[0]);
                acc[1] = fmaf(bf2f((unsigned short)gv[i][1]), wg[i], acc[1]);
                acc[2] = fmaf(bf2f((unsigned short)gv[i][2]), wg[i], acc[2]);
                acc[3] = fmaf(bf2f((unsigned short)gv[i][3]), wg[i], acc[3]);
            }
        }
        // glob edges [sp, end)
        for (int b = sp; b < end; b += 4) {
            float  wg[4];
            short4v gv[4];
            #pragma unroll
            for (int i = 0; i < 4; ++i) {
                const int sl = b + i;
                const int sc = sl < end ? sl : end - 1;
                const float wv = expv[(sc << 2) + h];
                wg[i] = (sl < end) ? wv : 0.f;
                const int row = rows[sc];
                gv[i] = *(const short4v*)(h2 + ((size_t)row << 6) + (c << 2));
            }
            #pragma unroll
            for (int i = 0; i < 4; ++i) {
                s += wg[i];
                accg[0] = fmaf(bf2f((unsigned short)gv[i][0]), wg[i], accg[0]);
                accg[1] = fmaf(bf2f((unsigned short)gv[i][1]), wg[i], accg[1]);
                accg[2] = fmaf(bf2f((unsigned short)gv[i][2]), wg[i], accg[2]);
                accg[3] = fmaf(bf2f((unsigned short)gv[i][3]), wg[i], accg[3]);
            }
        }

        const float inv = (end > start) ? 1.f / s : 0.f;
        char* p = agg_lds + (h * 16 + ln) * AGSTR;
        short4v ob, og;
        ob[0] = (short)f2bf(acc[0] * inv);  ob[1] = (short)f2bf(acc[1] * inv);
        ob[2] = (short)f2bf(acc[2] * inv);  ob[3] = (short)f2bf(acc[3] * inv);
        og[0] = (short)f2bf(accg[0] * inv); og[1] = (short)f2bf(accg[1] * inv);
        og[2] = (short)f2bf(accg[2] * inv); og[3] = (short)f2bf(accg[3] * inv);
        *(short4v*)(p + 8 * c)       = ob;   // bond k = 4c..4c+3
        *(short4v*)(p + 128 + 8 * c) = og;   // glob k = 64+4c..+3
    }
    __syncthreads();

    // ---- Phase B: wave w = head w; 4 its x 4 K-steps = 16 MFMAs ----
    {
        const int g = l >> 4;
        #pragma unroll
        for (int it = 0; it < 4; ++it) {
            f32x4 oacc = {};
            #pragma unroll
            for (int st = 0; st < 4; ++st) {
                bf16x8 a = *(const bf16x8*)(wt2 + ((((w << 6) + (it << 4) + c) << 7) + 32 * st + 8 * g));
                bf16x8 bfrag = *(const bf16x8*)(agg_lds + (w * 16 + c) * AGSTR + 64 * st + 16 * g);
                oacc = __builtin_amdgcn_mfma_f32_16x16x32_bf16(a, bfrag, oacc, 0, 0, 0);
            }
            *(f32x4*)(out + ((size_t)(n0 + c) << 8) + (w << 6) + (it << 4) + (g << 2)) = oacc;
        }
    }
}

// ---------------------------------------------------------------------------
extern "C" void kernel_launch(void* const* d_in, const int* in_sizes, int n_in,
                              void* d_out, int out_size, void* d_ws, size_t ws_size,
                              hipStream_t stream)
{
    const float* master = (const float*)d_in[0];
    const float* bond   = (const float*)d_in[1];
    const float* glob   = (const float*)d_in[2];
    const float* aW0 = (const float*)d_in[3];
    const float* ab0 = (const float*)d_in[4];
    const float* aW1 = (const float*)d_in[5];
    const float* ab1 = (const float*)d_in[6];
    const float* aW2 = (const float*)d_in[7];
    const float* bW0 = (const float*)d_in[8];
    const float* bb0 = (const float*)d_in[9];
    const float* bW1 = (const float*)d_in[10];
    const float* bb1 = (const float*)d_in[11];
    const float* bW2 = (const float*)d_in[12];
    const float* gW0 = (const float*)d_in[13];
    const float* gb0 = (const float*)d_in[14];
    const float* gW1 = (const float*)d_in[15];
    const float* gb1 = (const float*)d_in[16];
    const float* gW2 = (const float*)d_in[17];
    const float* attn_l = (const float*)d_in[18];
    const float* attn_r = (const float*)d_in[19];
    const int* e1_src = (const int*)d_in[20];
    const int* e1_dst = (const int*)d_in[21];
    const int* e2_src = (const int*)d_in[22];
    const int* e2_dst = (const int*)d_in[23];
    float* out = (float*)d_out;

    // workspace layout
    unsigned short* h2 = (unsigned short*)d_ws;          // (NB+NG)*64 bf16
    float* er   = (float*)(h2 + (size_t)(NB + NG) * 64); // NM*4
    float* el_b = er + (size_t)NM * 4;                   // NB*4
    float* el_g = el_b + (size_t)NB * 4;                 // NG*4
    int* counts  = (int*)(el_g + (size_t)NG * 4);        // NMP
    int* offsets = counts + NMP;                         // NMP
    int* cursor  = offsets + NMP;                        // NMP
    int* cursor2 = cursor + NMP;                         // NMP
    int* rows    = cursor2 + NMP;                        // NE (+pad below)
    float4* expv = (float4*)(rows + NE + 16);            // NE float4
    int* prefix_inc = (int*)(expv + NE);                 // NMP
    int* blocksums  = prefix_inc + NMP;                  // 512
    float* effR  = (float*)(blocksums + 512);            // 256
    float* effLB = effR + 256;                           // 256
    float* effLG = effLB + 256;                          // 256
    short* wt2 = (short*)(effLG + 256);                  // 32768
    short* wtA = wt2 + 32768;                            // 8192 (W0t+W1t)
    short* wtB = wtA + 8192;
    short* wtG = wtB + 8192;

    hipMemsetAsync(counts, 0, sizeof(int) * NM, stream);

    // weight prep
    WAll wa;
    wa.e[0] = {aW0, wtA,         64,     0};
    wa.e[1] = {aW1, wtA + 4096,  64,  4096};
    wa.e[2] = {bW0, wtB,         64,  8192};
    wa.e[3] = {bW1, wtB + 4096,  64, 12288};
    wa.e[4] = {gW0, wtG,         64, 16384};
    wa.e[5] = {gW1, wtG + 4096,  64, 20480};
    wprep_all_kernel<<<96, 256, 0, stream>>>(wa);
    wt2prep_kernel<<<128, 256, 0, stream>>>(bW2, gW2, wt2);
    Eff3 ef;
    ef.W2[0] = aW2; ef.attn[0] = attn_r; ef.eff[0] = effR;
    ef.W2[1] = bW2; ef.attn[1] = attn_l; ef.eff[1] = effLB;
    ef.W2[2] = gW2; ef.attn[2] = attn_l; ef.eff[2] = effLG;
    eff3_kernel<<<3, 256, 0, stream>>>(ef);

    // merged MLP launch: bond (3125) | glob (79) | master (1563)
    MlpArgs ma;
    ma.x[0] = bond;   ma.N[0] = NB; ma.W0t[0] = wtB; ma.b0[0] = bb0;
    ma.W1t[0] = wtB + 4096; ma.b1[0] = bb1; ma.eff[0] = effLB;
    ma.score[0] = el_b; ma.h2o[0] = h2;
    ma.x[1] = glob;   ma.N[1] = NG; ma.W0t[1] = wtG; ma.b0[1] = gb0;
    ma.W1t[1] = wtG + 4096; ma.b1[1] = gb1; ma.eff[1] = effLG;
    ma.score[1] = el_g; ma.h2o[1] = h2 + (size_t)NB * 64;
    ma.x[2] = master; ma.N[2] = NM; ma.W0t[2] = wtA; ma.b0[2] = ab0;
    ma.W1t[2] = wtA + 4096; ma.b1[2] = ab1; ma.eff[2] = effR;
    ma.score[2] = er;   ma.h2o[2] = nullptr;
    ma.bstart[0] = 0;
    ma.bstart[1] = (NB + 63) / 64;                       // 3125
    ma.bstart[2] = ma.bstart[1] + (NG + 63) / 64;        // 3204
    const int nblk = ma.bstart[2] + (NM + 63) / 64;      // 4767
    mlp2_all_kernel<<<nblk, 256, 0, stream>>>(ma);

    hist_kernel<<<(NE + 255) / 256, 256, 0, stream>>>(e1_dst, e2_dst, counts);
    scan1_kernel<<<SCAN_BLOCKS, 256, 0, stream>>>(counts, prefix_inc, blocksums);
    scan2_kernel<<<1, 512, 0, stream>>>(blocksums);
    scan3_kernel<<<SCAN_BLOCKS + 1, 256, 0, stream>>>(counts, prefix_inc, blocksums,
                                                      offsets, cursor, cursor2);
    fill_kernel<<<(NE + 255) / 256, 256, 0, stream>>>(e1_src, e1_dst, e2_src, e2_dst,
                                                      er, el_b, el_g,
                                                      cursor, cursor2, rows, expv);
    aggregate_fused_kernel<<<NM / 16, 256, 0, stream>>>(offsets, cursor2, rows,
                                                        (const float*)expv,
                                                        h2, wt2, out);
}